// Round 7
// baseline (1318.059 us; speedup 1.0000x reference)
//
#include <hip/hip_runtime.h>
#include <hip/hip_bf16.h>
#include <hip/hip_cooperative_groups.h>

namespace cg = cooperative_groups;

#define NPTS 1000000
#define NVOX 200000
#define NCLS 20
#define NBM 3907   // ceil(NPTS/256)
#define NBS 196    // ceil(NVOX/1024)

typedef __hip_bfloat16 bf16;
typedef __attribute__((ext_vector_type(8))) short bf16x8_t;
typedef __attribute__((ext_vector_type(4))) float f32x4_t;
#define MFMA16(a, b, c) __builtin_amdgcn_mfma_f32_16x16x32_bf16(a, b, c, 0, 0, 0)

// ---------- workspace layout (fp32 words) ----------
constexpr size_t L_PTSC = 0;                          // (unused; retained layout)
constexpr size_t L_PV   = L_PTSC + (size_t)NPTS * 4;  // N int32 voxel ids
constexpr size_t L_BID  = L_PV + NPTS;                // N int32 batch ids
constexpr size_t L_CNT  = L_BID + NPTS;               // V counts (zero)
constexpr size_t L_BSUM = L_CNT + NVOX;               // 8 x 256 replicated (zero)
constexpr size_t L_BCNT = L_BSUM + 2048;              // 4 (zero)
constexpr size_t L_GATE = L_BCNT + 4;                 // 256
constexpr size_t L_FLAG = L_GATE + 256;               // 4 (unused)
constexpr size_t L_OFFS = L_FLAG + 4;                 // V
constexpr size_t L_OFFW = L_OFFS + NVOX;              // V (unused)
constexpr size_t L_BS1  = L_OFFW + NVOX;              // 256 block sums
constexpr size_t L_BB   = L_BS1 + 256;                // 256 block bases
constexpr size_t L_IDX  = L_BB + 256;                 // N rank (within-voxel arrival order)
constexpr size_t L_W    = L_IDX + NPTS;               // folded weights fp32
// weight offsets inside W
constexpr int O_PE1W = 0;      constexpr int O_PE1B = 128;
constexpr int O_PE2W = 160;    constexpr int O_PE2B = 2208;
constexpr int O_PE3W = 2272;   constexpr int O_PE3B = 4320;
constexpr int O_VE1W = 4352;   constexpr int O_VE1B = 5376;
constexpr int O_VE2W = 5408;   constexpr int O_VE2B = 6432;
constexpr int O_FUW  = 6464;   constexpr int O_FUB  = 10560;
constexpr int O_SE1W = 10624;  constexpr int O_SE1B = 10880;
constexpr int O_SE2W = 10884;  constexpr int O_SE2B = 11140;
constexpr int O_CLS1W = 11204; constexpr int O_CLS1B = 13252;
constexpr int O_CLS2W = 13284;
constexpr int O_AUX1W = 13924; constexpr int O_AUX1B = 14948;
constexpr int O_AUX2W = 14980;
constexpr int W_TOTAL = 15620;
constexpr size_t L_WT  = L_W + W_TOTAL;               // bf16 transposed weights
static_assert((L_WT * 4) % 16 == 0, "WT alignment");
// WT sub-offsets in u16 units
constexpr int WT_FU = 0;          // [64][64]
constexpr int WT_C1 = 4096;       // [32][64]
constexpr int WT_C2 = 6144;       // [32][32]
constexpr int WT_2H = 7168;       // pe2 [64 n][32 k] hi
constexpr int WT_2L = 9216;       // pe2 lo
constexpr int WT_3H = 11264;      // pe3 [32 n][64 k] hi
constexpr int WT_3L = 13312;      // pe3 lo
constexpr int WT_U16 = 15360;
constexpr size_t L_VFU = L_WT + WT_U16 / 2;
constexpr size_t L_PFQ = L_VFU + (size_t)NVOX * 16;   // N*16 packed bf16 pairs (orig order)
constexpr size_t L_PFS = L_PFQ + (size_t)NPTS * 16;   // N*16 packed bf16 pairs (sorted order)
static_assert((L_VFU * 4) % 16 == 0, "vf alignment");
static_assert((L_PFQ * 4) % 16 == 0, "pf alignment");
static_assert((L_PFS * 4) % 16 == 0, "pfs alignment");

static __device__ __forceinline__ float b2f(bf16 v) { return __bfloat162float(v); }
static __device__ __forceinline__ float us2f(unsigned short u) { return __uint_as_float((unsigned)u << 16); }
static __device__ __forceinline__ unsigned short f2us(float f) {
    unsigned u = __float_as_uint(f);
    u += 0x7fffu + ((u >> 16) & 1u);
    return (unsigned short)(u >> 16);
}
static __device__ __forceinline__ unsigned pack2(float a, float b) {
    return (unsigned)f2us(a) | ((unsigned)f2us(b) << 16);
}
static __device__ __forceinline__ void unpack2(unsigned u, float& a, float& b) {
    a = __uint_as_float(u << 16);
    b = __uint_as_float(u & 0xffff0000u);
}
static __device__ __forceinline__ float rdf(const void* p, size_t idx, int fp32) {
    return fp32 ? ((const float*)p)[idx] : b2f(((const bf16*)p)[idx]);
}
static __device__ __forceinline__ int detect_fp32(const void* pts_raw) {
    const unsigned short* ptsu = (const unsigned short*)pts_raw;
    return (ptsu[1] == 0 && ptsu[11] == 0) ? 1 : 0;
}
static __device__ __forceinline__ int detect_i64(const void* pv_raw) {
    const unsigned* pvu = (const unsigned*)pv_raw;
    return (pvu[1] == 0 && pvu[3] == 0 && pvu[5] == 0 && pvu[7] == 0) ? 1 : 0;
}

template <int K, int M, bool RELU, bool BIAS>
static __device__ __forceinline__ void dense(const float* __restrict__ x, float* __restrict__ y,
                                             const float* __restrict__ w, const float* __restrict__ b) {
#pragma unroll
    for (int j = 0; j < M; ++j) {
        float a = BIAS ? b[j] : 0.f;
#pragma unroll
        for (int k = 0; k < K; ++k) a = fmaf(x[k], w[k * M + j], a);
        y[j] = RELU ? fmaxf(a, 0.f) : a;
    }
}

static __device__ __forceinline__ int block_excl_scan(int v, int t) {
    __shared__ int sh[2][256];
    int cur = 0;
    sh[0][t] = v; __syncthreads();
#pragma unroll
    for (int off = 1; off < 256; off <<= 1) {
        int val = sh[cur][t];
        if (t >= off) val += sh[cur][t - off];
        sh[cur ^ 1][t] = val; __syncthreads();
        cur ^= 1;
    }
    return sh[cur][t] - v;
}

struct WPtrs {
    const void *pe_w1, *pe_g1, *pe_b1, *pe_w2, *pe_g2, *pe_b2, *pe_w3, *pe_g3, *pe_b3;
    const void *ve_w1, *ve_g1, *ve_b1, *ve_w2, *ve_g2, *ve_b2;
    const void *fu_w, *fu_g, *fu_b;
    const void *se_w1, *se_b1, *se_w2, *se_b2;
    const void *cls_w1, *cls_g1, *cls_b1, *cls_w2;
    const void *aux_w1, *aux_g1, *aux_b1, *aux_w2;
};

static __device__ void foldw(float* d, const void* w, const void* g, int K, int M, int fp32) {
    const float INV = 0.9999950000374997f;  // 1/sqrt(1+1e-5)
    for (int idx = threadIdx.x; idx < K * M; idx += 256)
        d[idx] = rdf(w, idx, fp32) * (rdf(g, idx % M, fp32) * INV);
}
static __device__ void cpv(float* d, const void* s, int n, int fp32) {
    for (int idx = threadIdx.x; idx < n; idx += 256) d[idx] = rdf(s, idx, fp32);
}

// weight prep body (used by k0_prep and mega phase P)
static __device__ void prep_dev(const WPtrs& p, int f, float* W, unsigned short* WT) {
    foldw(W + O_PE1W, p.pe_w1, p.pe_g1, 4, 32, f);   cpv(W + O_PE1B, p.pe_b1, 32, f);
    foldw(W + O_PE2W, p.pe_w2, p.pe_g2, 32, 64, f);  cpv(W + O_PE2B, p.pe_b2, 64, f);
    foldw(W + O_PE3W, p.pe_w3, p.pe_g3, 64, 32, f);  cpv(W + O_PE3B, p.pe_b3, 32, f);
    foldw(W + O_VE1W, p.ve_w1, p.ve_g1, 32, 32, f);  cpv(W + O_VE1B, p.ve_b1, 32, f);
    foldw(W + O_VE2W, p.ve_w2, p.ve_g2, 32, 32, f);  cpv(W + O_VE2B, p.ve_b2, 32, f);
    foldw(W + O_FUW,  p.fu_w,  p.fu_g,  64, 64, f);  cpv(W + O_FUB,  p.fu_b, 64, f);
    cpv(W + O_SE1W, p.se_w1, 256, f);  cpv(W + O_SE1B, p.se_b1, 4, f);
    cpv(W + O_SE2W, p.se_w2, 256, f);  cpv(W + O_SE2B, p.se_b2, 64, f);
    foldw(W + O_CLS1W, p.cls_w1, p.cls_g1, 64, 32, f); cpv(W + O_CLS1B, p.cls_b1, 32, f);
    cpv(W + O_CLS2W, p.cls_w2, 640, f);
    foldw(W + O_AUX1W, p.aux_w1, p.aux_g1, 32, 32, f); cpv(W + O_AUX1B, p.aux_b1, 32, f);
    cpv(W + O_AUX2W, p.aux_w2, 640, f);
    __syncthreads();
    unsigned short* wtfu = WT + WT_FU;
    unsigned short* wtc1 = WT + WT_C1;
    unsigned short* wtc2 = WT + WT_C2;
    unsigned short* wt2h = WT + WT_2H;
    unsigned short* wt2l = WT + WT_2L;
    unsigned short* wt3h = WT + WT_3H;
    unsigned short* wt3l = WT + WT_3L;
    for (int idx = threadIdx.x; idx < 4096; idx += 256) {
        int n = idx >> 6, k = idx & 63;
        wtfu[idx] = f2us(W[O_FUW + k * 64 + n]);
    }
    for (int idx = threadIdx.x; idx < 2048; idx += 256) {
        int n = idx >> 6, k = idx & 63;
        wtc1[idx] = f2us(W[O_CLS1W + k * 32 + n]);
    }
    for (int idx = threadIdx.x; idx < 1024; idx += 256) {
        int n = idx >> 5, k = idx & 31;
        wtc2[idx] = (n < NCLS) ? f2us(W[O_CLS2W + k * NCLS + n]) : (unsigned short)0;
    }
    for (int idx = threadIdx.x; idx < 2048; idx += 256) {
        int n = idx >> 5, k = idx & 31;
        float v = W[O_PE2W + k * 64 + n];
        unsigned short hi = f2us(v);
        wt2h[idx] = hi;
        wt2l[idx] = f2us(v - us2f(hi));
    }
    for (int idx = threadIdx.x; idx < 2048; idx += 256) {
        int n = idx >> 6, k = idx & 63;
        float v = W[O_PE3W + k * 32 + n];
        unsigned short hi = f2us(v);
        wt3h[idx] = hi;
        wt3l[idx] = f2us(v - us2f(hi));
    }
}

struct MegaArgs {
    WPtrs p;
    const void* pts_raw;
    const void* pv_raw;
    float* W;
    unsigned short* WT;
    int* pvN; int* bidN; int* cnt; float* bcnt; int* rank;
    int* offs; int* bs1; int* bb;
    float* bsum8; float* gate;
    unsigned* vf_u; uint4* pf_q; uint4* pf_s;
    void* out;
};

// ================= the mega kernel (cooperative) =================
__global__ __launch_bounds__(256, 4) void k_mega(MegaArgs a) {
    cg::grid_group grid = cg::this_grid();
    int t = threadIdx.x;
    int bx = blockIdx.x;
    int G = gridDim.x;
    int lane = t & 63, w = t >> 6;
    int m = lane & 15, quad = lane >> 4;
    int fp32 = detect_fp32(a.pts_raw);
    int i64 = detect_i64(a.pv_raw);

    __shared__ __align__(16) unsigned char pool[23552];
    auto hth = (unsigned short(*)[16][72])(pool);           // M view
    auto htl = (unsigned short(*)[16][72])(pool + 9216);
    auto ptb = (unsigned short(*)[16][40])(pool + 18432);
    auto ft = (unsigned short(*)[16][72])(pool);            // F view
    auto ht = (unsigned short(*)[16][40])(pool + 9216);
    auto ot = (float(*)[16][20])(pool + 14336);
    __shared__ int sbid[256];
    __shared__ int sb0s, sflag;
    __shared__ float redw[4][64];
    __shared__ int red1[256];
    __shared__ float sg[256];
    __shared__ float m4[4][64];
    __shared__ float hid4[4][4];

    // ===== P: weight prep =====
    if (bx == 0) prep_dev(a.p, fp32, a.W, a.WT);
    grid.sync();

    const float* W = a.W;
    const unsigned short* WTfu = a.WT + WT_FU;
    const unsigned short* WTc1 = a.WT + WT_C1;
    const unsigned short* WTc2 = a.WT + WT_C2;

    // ===== M: point MLP + histogram tail =====
    {
        const unsigned short* WT2H = a.WT + WT_2H;
        const unsigned short* WT2L = a.WT + WT_2L;
        const unsigned short* WT3H = a.WT + WT_3H;
        const unsigned short* WT3L = a.WT + WT_3L;
        float w1[32], b1[8];
#pragma unroll
        for (int k = 0; k < 4; ++k)
#pragma unroll
            for (int j = 0; j < 8; ++j) w1[k * 8 + j] = W[O_PE1W + k * 32 + quad * 8 + j];
#pragma unroll
        for (int j = 0; j < 8; ++j) b1[j] = W[O_PE1B + quad * 8 + j];
        bf16x8_t b2h[4], b2l[4], b3h[2][2], b3l[2][2];
        float bias2[4], bias3[2];
#pragma unroll
        for (int tn = 0; tn < 4; ++tn) {
            b2h[tn] = *(const bf16x8_t*)(WT2H + (tn * 16 + m) * 32 + quad * 8);
            b2l[tn] = *(const bf16x8_t*)(WT2L + (tn * 16 + m) * 32 + quad * 8);
            bias2[tn] = W[O_PE2B + tn * 16 + m];
        }
#pragma unroll
        for (int tn = 0; tn < 2; ++tn) {
#pragma unroll
            for (int kh = 0; kh < 2; ++kh) {
                b3h[tn][kh] = *(const bf16x8_t*)(WT3H + (tn * 16 + m) * 64 + kh * 32 + quad * 8);
                b3l[tn][kh] = *(const bf16x8_t*)(WT3L + (tn * 16 + m) * 64 + kh * 32 + quad * 8);
            }
            bias3[tn] = W[O_PE3B + tn * 16 + m];
        }

        for (int vb = bx; vb < NBM; vb += G) {
            int i0 = vb * 256;
            int nval = NPTS - i0; if (nval > 256) nval = 256;
            int ntiles = (nval - w * 64 >= 64) ? 4 : 0;
#pragma unroll 1
            for (int tt = 0; tt < ntiles; ++tt) {
                int rbase = i0 + w * 64 + tt * 16;
                int arow = rbase + m;
                float4 c;
                c.x = rdf(a.pts_raw, (size_t)arow * 5 + 1, fp32);
                c.y = rdf(a.pts_raw, (size_t)arow * 5 + 2, fp32);
                c.z = rdf(a.pts_raw, (size_t)arow * 5 + 3, fp32);
                c.w = rdf(a.pts_raw, (size_t)arow * 5 + 4, fp32);
                union { unsigned u[4]; bf16x8_t v; } ah, al;
#pragma unroll
                for (int pp = 0; pp < 4; ++pp) {
                    unsigned hu = 0, lu = 0;
#pragma unroll
                    for (int s = 0; s < 2; ++s) {
                        int j = 2 * pp + s;
                        float h = b1[j];
                        h = fmaf(c.x, w1[0 * 8 + j], h);
                        h = fmaf(c.y, w1[1 * 8 + j], h);
                        h = fmaf(c.z, w1[2 * 8 + j], h);
                        h = fmaf(c.w, w1[3 * 8 + j], h);
                        h = fmaxf(h, 0.f);
                        unsigned short hi = f2us(h);
                        unsigned short lo = f2us(h - us2f(hi));
                        hu |= (unsigned)hi << (16 * s);
                        lu |= (unsigned)lo << (16 * s);
                    }
                    ah.u[pp] = hu; al.u[pp] = lu;
                }
#pragma unroll
                for (int tn = 0; tn < 4; ++tn) {
                    f32x4_t acc = {0.f, 0.f, 0.f, 0.f};
                    acc = MFMA16(ah.v, b2h[tn], acc);
                    acc = MFMA16(ah.v, b2l[tn], acc);
                    acc = MFMA16(al.v, b2h[tn], acc);
#pragma unroll
                    for (int e = 0; e < 4; ++e) {
                        float v = fmaxf(acc[e] + bias2[tn], 0.f);
                        unsigned short hi = f2us(v);
                        hth[w][quad * 4 + e][tn * 16 + m] = hi;
                        htl[w][quad * 4 + e][tn * 16 + m] = f2us(v - us2f(hi));
                    }
                }
                bf16x8_t x0h = *(const bf16x8_t*)&hth[w][m][quad * 8];
                bf16x8_t x1h = *(const bf16x8_t*)&hth[w][m][32 + quad * 8];
                bf16x8_t x0l = *(const bf16x8_t*)&htl[w][m][quad * 8];
                bf16x8_t x1l = *(const bf16x8_t*)&htl[w][m][32 + quad * 8];
#pragma unroll
                for (int tn = 0; tn < 2; ++tn) {
                    f32x4_t acc = {0.f, 0.f, 0.f, 0.f};
                    acc = MFMA16(x0h, b3h[tn][0], acc);
                    acc = MFMA16(x1h, b3h[tn][1], acc);
                    acc = MFMA16(x0h, b3l[tn][0], acc);
                    acc = MFMA16(x1h, b3l[tn][1], acc);
                    acc = MFMA16(x0l, b3h[tn][0], acc);
                    acc = MFMA16(x1l, b3h[tn][1], acc);
#pragma unroll
                    for (int e = 0; e < 4; ++e)
                        ptb[w][quad * 4 + e][tn * 16 + m] = f2us(fmaxf(acc[e] + bias3[tn], 0.f));
                }
                uint4 q = *(const uint4*)&ptb[w][m][quad * 8];
                a.pf_q[(size_t)arow * 4 + quad] = q;
            }
            int i = i0 + t;
            bool valid = t < nval;
            int b = 0, rk = 0;
            if (valid) {
                b = (int)rdf(a.pts_raw, (size_t)i * 5, fp32);
                a.bidN[i] = b;
                int v = i64 ? (int)((const long long*)a.pv_raw)[i] : ((const int*)a.pv_raw)[i];
                a.pvN[i] = v;
                rk = atomicAdd(&a.cnt[v], 1);
            }
            if (t == 0) { sb0s = b; sflag = 1; }
            __syncthreads();
            if (valid && b != sb0s) sflag = 0;
            __syncthreads();
            if (sflag) {
                if (t == 0) atomicAdd(&a.bcnt[sb0s], (float)nval);
            } else if (valid) {
                atomicAdd(&a.bcnt[b], 1.f);
            }
            if (valid) a.rank[i] = rk;
            __syncthreads();
        }
    }
    grid.sync();

    // ===== S1 =====
    for (int c = bx; c < NBS; c += G) {
        int base = c * 1024 + t * 4;
        int s = 0;
#pragma unroll
        for (int k = 0; k < 4; ++k) { int idx = base + k; if (idx < NVOX) s += a.cnt[idx]; }
        red1[t] = s; __syncthreads();
        for (int off = 128; off > 0; off >>= 1) { if (t < off) red1[t] += red1[t + off]; __syncthreads(); }
        if (t == 0) a.bs1[c] = red1[0];
        __syncthreads();
    }
    grid.sync();

    // ===== S2 (block 0) =====
    if (bx == 0) {
        int v = (t < NBS) ? a.bs1[t] : 0;
        int e = block_excl_scan(v, t);
        a.bb[t] = e;
    }
    grid.sync();

    // ===== S3 =====
    for (int c = bx; c < NBS; c += G) {
        int base = c * 1024 + t * 4;
        int cc[4]; int s = 0;
#pragma unroll
        for (int k = 0; k < 4; ++k) { int idx = base + k; cc[k] = (idx < NVOX) ? a.cnt[idx] : 0; s += cc[k]; }
        int run = a.bb[c] + block_excl_scan(s, t);
#pragma unroll
        for (int k = 0; k < 4; ++k) {
            int idx = base + k;
            if (idx < NVOX) { a.offs[idx] = run; run += cc[k]; }
        }
        __syncthreads();
    }
    grid.sync();

    // ===== SC: scatter pf into sorted order =====
    for (long long idx = (long long)bx * 256 + t; idx < (long long)NPTS * 4; idx += (long long)G * 256) {
        int i = (int)(idx >> 2), q = (int)(idx & 3);
        int sp = a.offs[a.pvN[i]] + a.rank[i];
        a.pf_s[(size_t)sp * 4 + q] = a.pf_q[(size_t)i * 4 + q];
    }
    grid.sync();

    // ===== V: per-voxel max + voxel MLP + aux =====
    for (int v = bx * 256 + t; v < NVOX; v += G * 256) {
        float mx[32];
#pragma unroll
        for (int c = 0; c < 32; ++c) mx[c] = 0.f;
        int s = a.offs[v], n = a.cnt[v];
        for (int pp = 0; pp < n; ++pp) {
            size_t base = (size_t)(s + pp) * 4;
#pragma unroll
            for (int tt = 0; tt < 4; ++tt) {
                uint4 q = a.pf_s[base + tt];
                float x, y;
                unpack2(q.x, x, y); mx[8*tt+0] = fmaxf(mx[8*tt+0], x); mx[8*tt+1] = fmaxf(mx[8*tt+1], y);
                unpack2(q.y, x, y); mx[8*tt+2] = fmaxf(mx[8*tt+2], x); mx[8*tt+3] = fmaxf(mx[8*tt+3], y);
                unpack2(q.z, x, y); mx[8*tt+4] = fmaxf(mx[8*tt+4], x); mx[8*tt+5] = fmaxf(mx[8*tt+5], y);
                unpack2(q.w, x, y); mx[8*tt+6] = fmaxf(mx[8*tt+6], x); mx[8*tt+7] = fmaxf(mx[8*tt+7], y);
            }
        }
        float v1[32], vf[32], a1[32], o[20];
        dense<32, 32, true, true>(mx, v1, W + O_VE1W, W + O_VE1B);
        dense<32, 32, true, true>(v1, vf, W + O_VE2W, W + O_VE2B);
#pragma unroll
        for (int c = 0; c < 16; ++c) a.vf_u[(size_t)v * 16 + c] = pack2(vf[2*c], vf[2*c+1]);
        dense<32, 32, true, true>(v1, a1, W + O_AUX1W, W + O_AUX1B);
        dense<32, 20, false, false>(a1, o, W + O_AUX2W, nullptr);
        if (fp32) {
            float* auxf = (float*)a.out + (size_t)NPTS * NCLS + (size_t)v * NCLS;
#pragma unroll
            for (int tt = 0; tt < NCLS; ++tt) auxf[tt] = o[tt];
        } else {
            unsigned* auxu = (unsigned*)((bf16*)a.out + (size_t)NPTS * NCLS);
#pragma unroll
            for (int tt = 0; tt < 10; ++tt) auxu[(size_t)v * 10 + tt] = pack2(o[2*tt], o[2*tt+1]);
        }
    }
    grid.sync();

    bf16x8_t bfu0[4], bfu1[4];
    float biasfu[4];
#pragma unroll
    for (int tn = 0; tn < 4; ++tn) {
        bfu0[tn] = *(const bf16x8_t*)(WTfu + (tn * 16 + m) * 64 + quad * 8);
        bfu1[tn] = *(const bf16x8_t*)(WTfu + (tn * 16 + m) * 64 + 32 + quad * 8);
        biasfu[tn] = W[O_FUB + tn * 16 + m];
    }
    const uint4* vf_q = (const uint4*)a.vf_u;

    // ===== D: fuse GEMM + per-batch sums =====
    for (int vb = bx; vb < NBM; vb += G) {
        int i0 = vb * 256;
        int nval = NPTS - i0; if (nval > 256) nval = 256;
        if (t < nval) sbid[t] = a.bidN[i0 + t];
        if (t == 0) sflag = (a.bidN[i0] == a.bidN[i0 + nval - 1]) ? 1 : 0;
        __syncthreads();
        int uni = sflag;
        int b0 = sbid[0];
        int rep = (vb & 7) * 256;
        int ntiles = (nval - w * 64 >= 64) ? 4 : 0;
        float csum[4] = {0.f, 0.f, 0.f, 0.f};
#pragma unroll
        for (int tt = 0; tt < 4; ++tt) {
            if (tt >= ntiles) break;
            int rbase = i0 + w * 64 + tt * 16;
            int arow = rbase + m;
            int pvr = a.pvN[arow];
            uint4 va = vf_q[(size_t)pvr * 4 + quad];
            uint4 vb2 = a.pf_q[(size_t)arow * 4 + quad];
            bf16x8_t a0 = *(bf16x8_t*)&va;
            bf16x8_t a1 = *(bf16x8_t*)&vb2;
            float f[4][4];
#pragma unroll
            for (int tn = 0; tn < 4; ++tn) {
                f32x4_t acc = {0.f, 0.f, 0.f, 0.f};
                acc = MFMA16(a0, bfu0[tn], acc);
                acc = MFMA16(a1, bfu1[tn], acc);
#pragma unroll
                for (int e = 0; e < 4; ++e) f[tn][e] = fmaxf(acc[e] + biasfu[tn], 0.f);
            }
            if (uni) {
#pragma unroll
                for (int tn = 0; tn < 4; ++tn) {
                    float s = f[tn][0] + f[tn][1] + f[tn][2] + f[tn][3];
                    s += __shfl_xor(s, 16);
                    s += __shfl_xor(s, 32);
                    csum[tn] += s;
                }
            } else {
#pragma unroll
                for (int tn = 0; tn < 4; ++tn)
#pragma unroll
                    for (int e = 0; e < 4; ++e)
                        atomicAdd(&a.bsum8[rep + sbid[rbase - i0 + quad * 4 + e] * 64 + tn * 16 + m], f[tn][e]);
            }
        }
        if (uni) {
            float mine = quad == 0 ? csum[0] : quad == 1 ? csum[1] : quad == 2 ? csum[2] : csum[3];
            redw[w][quad * 16 + m] = mine;
            __syncthreads();
            if (t < 64) {
                float s = redw[0][t] + redw[1][t] + redw[2][t] + redw[3][t];
                atomicAdd(&a.bsum8[rep + b0 * 64 + t], s);
            }
        }
        __syncthreads();
    }
    grid.sync();

    // ===== E: SE gate (block 0) =====
    if (bx == 0) {
        int b = t >> 6, c = t & 63;
        float s = 0.f;
#pragma unroll
        for (int r = 0; r < 8; ++r) s += a.bsum8[r * 256 + t];
        m4[b][c] = s / fmaxf(a.bcnt[b], 1.f);
        __syncthreads();
        if (c < 4) {
            const float* ww = W + O_SE1W;
            float x = (W + O_SE1B)[c];
            for (int k = 0; k < 64; ++k) x = fmaf(m4[b][k], ww[k * 4 + c], x);
            hid4[b][c] = fmaxf(x, 0.f);
        }
        __syncthreads();
        const float* w2 = W + O_SE2W;
        float g = (W + O_SE2B)[c];
#pragma unroll
        for (int h = 0; h < 4; ++h) g = fmaf(hid4[b][h], w2[h * 64 + c], g);
        a.gate[t] = 1.f + 1.f / (1.f + expf(-g));
    }
    grid.sync();

    // ===== F: fuse + gate + cls GEMMs + store =====
    {
        sg[t] = a.gate[t];
        bf16x8_t bc10[2], bc11[2], bc2[2];
        float biasc1[2];
#pragma unroll
        for (int tn = 0; tn < 2; ++tn) {
            bc10[tn] = *(const bf16x8_t*)(WTc1 + (tn * 16 + m) * 64 + quad * 8);
            bc11[tn] = *(const bf16x8_t*)(WTc1 + (tn * 16 + m) * 64 + 32 + quad * 8);
            bc2[tn]  = *(const bf16x8_t*)(WTc2 + (tn * 16 + m) * 32 + quad * 8);
            biasc1[tn] = W[O_CLS1B + tn * 16 + m];
        }
        for (int vb = bx; vb < NBM; vb += G) {
            int i0 = vb * 256;
            int nval = NPTS - i0; if (nval > 256) nval = 256;
            if (t < nval) sbid[t] = a.bidN[i0 + t];
            if (t == 0) sflag = (a.bidN[i0] == a.bidN[i0 + nval - 1]) ? 1 : 0;
            __syncthreads();
            int uni = sflag;
            int ntiles = (nval - w * 64 >= 64) ? 4 : 0;
#pragma unroll 1
            for (int tt = 0; tt < ntiles; ++tt) {
                int rbase = i0 + w * 64 + tt * 16;
                int arow = rbase + m;
                int pvr = a.pvN[arow];
                uint4 va = vf_q[(size_t)pvr * 4 + quad];
                uint4 vb2 = a.pf_q[(size_t)arow * 4 + quad];
                bf16x8_t a0 = *(bf16x8_t*)&va;
                bf16x8_t a1 = *(bf16x8_t*)&vb2;
                float gcol[4];
                if (uni) {
#pragma unroll
                    for (int tn = 0; tn < 4; ++tn) gcol[tn] = sg[sbid[0] * 64 + tn * 16 + m];
                }
#pragma unroll
                for (int tn = 0; tn < 4; ++tn) {
                    f32x4_t acc = {0.f, 0.f, 0.f, 0.f};
                    acc = MFMA16(a0, bfu0[tn], acc);
                    acc = MFMA16(a1, bfu1[tn], acc);
#pragma unroll
                    for (int e = 0; e < 4; ++e) {
                        float fv = fmaxf(acc[e] + biasfu[tn], 0.f);
                        float g = uni ? gcol[tn] : sg[sbid[rbase - i0 + quad * 4 + e] * 64 + tn * 16 + m];
                        ft[w][quad * 4 + e][tn * 16 + m] = f2us(fv * g);
                    }
                }
                bf16x8_t c0 = *(const bf16x8_t*)&ft[w][m][quad * 8];
                bf16x8_t c1 = *(const bf16x8_t*)&ft[w][m][32 + quad * 8];
#pragma unroll
                for (int tn = 0; tn < 2; ++tn) {
                    f32x4_t acc = {0.f, 0.f, 0.f, 0.f};
                    acc = MFMA16(c0, bc10[tn], acc);
                    acc = MFMA16(c1, bc11[tn], acc);
#pragma unroll
                    for (int e = 0; e < 4; ++e)
                        ht[w][quad * 4 + e][tn * 16 + m] = f2us(fmaxf(acc[e] + biasc1[tn], 0.f));
                }
                bf16x8_t d0 = *(const bf16x8_t*)&ht[w][m][quad * 8];
#pragma unroll
                for (int tn = 0; tn < 2; ++tn) {
                    f32x4_t acc = {0.f, 0.f, 0.f, 0.f};
                    acc = MFMA16(d0, bc2[tn], acc);
                    int c = tn * 16 + m;
                    if (c < NCLS) {
#pragma unroll
                        for (int e = 0; e < 4; ++e) ot[w][quad * 4 + e][c] = acc[e];
                    }
                }
                if (fp32) {
                    float* of = (float*)a.out + (size_t)rbase * NCLS;
#pragma unroll
                    for (int k = 0; k < 5; ++k) {
                        int idx = k * 64 + lane;
                        of[idx] = ((const float*)ot[w])[idx];
                    }
                } else {
                    unsigned* ow = (unsigned*)((unsigned short*)a.out + (size_t)rbase * NCLS);
#pragma unroll
                    for (int k = 0; k < 3; ++k) {
                        int idx = k * 64 + lane;
                        if (idx < 160) {
                            int pp = idx / 10, c2 = idx - pp * 10;
                            ow[idx] = pack2(ot[w][pp][2 * c2], ot[w][pp][2 * c2 + 1]);
                        }
                    }
                }
            }
            __syncthreads();
        }
    }
}

// ================= fallback chain (round-5, known-passing) =================
__global__ void k0_prep(WPtrs p, const void* __restrict__ pts_raw, float* __restrict__ W,
                        unsigned short* __restrict__ WT) {
    prep_dev(p, detect_fp32(pts_raw), W, WT);
}

__global__ __launch_bounds__(256) void k_scan1(const int* __restrict__ cnt, int* __restrict__ bs) {
    int t = threadIdx.x;
    int base = blockIdx.x * 1024 + t * 4;
    int s = 0;
#pragma unroll
    for (int k = 0; k < 4; ++k) { int idx = base + k; if (idx < NVOX) s += cnt[idx]; }
    __shared__ int red[256];
    red[t] = s; __syncthreads();
    for (int off = 128; off > 0; off >>= 1) { if (t < off) red[t] += red[t + off]; __syncthreads(); }
    if (t == 0) bs[blockIdx.x] = red[0];
}

__global__ __launch_bounds__(256) void k_scan2(const int* __restrict__ bs, int* __restrict__ bb, int nb) {
    int t = threadIdx.x;
    int v = (t < nb) ? bs[t] : 0;
    int e = block_excl_scan(v, t);
    bb[t] = e;
}

__global__ __launch_bounds__(256) void k_scan3(const int* __restrict__ cnt, const int* __restrict__ bb,
                                               int* __restrict__ offs) {
    int t = threadIdx.x;
    int base = blockIdx.x * 1024 + t * 4;
    int c[4]; int s = 0;
#pragma unroll
    for (int k = 0; k < 4; ++k) { int idx = base + k; c[k] = (idx < NVOX) ? cnt[idx] : 0; s += c[k]; }
    int run = bb[blockIdx.x] + block_excl_scan(s, t);
#pragma unroll
    for (int k = 0; k < 4; ++k) {
        int idx = base + k;
        if (idx < NVOX) { offs[idx] = run; run += c[k]; }
    }
}

__global__ __launch_bounds__(256) void k1_fused(const void* __restrict__ pts_raw,
                                                const void* __restrict__ pv_raw,
                                                const float* __restrict__ W,
                                                const unsigned short* __restrict__ WT2H,
                                                const unsigned short* __restrict__ WT2L,
                                                const unsigned short* __restrict__ WT3H,
                                                const unsigned short* __restrict__ WT3L,
                                                int* __restrict__ pvN,
                                                int* __restrict__ bidN,
                                                int* __restrict__ cnt,
                                                float* __restrict__ bcnt,
                                                int* __restrict__ rank,
                                                uint4* __restrict__ pf_q) {
    __shared__ __align__(16) unsigned short hth[4][16][72];
    __shared__ __align__(16) unsigned short htl[4][16][72];
    __shared__ __align__(16) unsigned short pt[4][16][40];
    int t = threadIdx.x;
    int lane = t & 63, w = t >> 6;
    int m = lane & 15, quad = lane >> 4;
    int i0 = blockIdx.x * 256;
    int fp32 = detect_fp32(pts_raw), i64 = detect_i64(pv_raw);

    float w1[32], b1[8];
#pragma unroll
    for (int k = 0; k < 4; ++k)
#pragma unroll
        for (int j = 0; j < 8; ++j) w1[k * 8 + j] = W[O_PE1W + k * 32 + quad * 8 + j];
#pragma unroll
    for (int j = 0; j < 8; ++j) b1[j] = W[O_PE1B + quad * 8 + j];
    bf16x8_t b2h[4], b2l[4], b3h[2][2], b3l[2][2];
    float bias2[4], bias3[2];
#pragma unroll
    for (int tn = 0; tn < 4; ++tn) {
        b2h[tn] = *(const bf16x8_t*)(WT2H + (tn * 16 + m) * 32 + quad * 8);
        b2l[tn] = *(const bf16x8_t*)(WT2L + (tn * 16 + m) * 32 + quad * 8);
        bias2[tn] = W[O_PE2B + tn * 16 + m];
    }
#pragma unroll
    for (int tn = 0; tn < 2; ++tn) {
#pragma unroll
        for (int kh = 0; kh < 2; ++kh) {
            b3h[tn][kh] = *(const bf16x8_t*)(WT3H + (tn * 16 + m) * 64 + kh * 32 + quad * 8);
            b3l[tn][kh] = *(const bf16x8_t*)(WT3L + (tn * 16 + m) * 64 + kh * 32 + quad * 8);
        }
        bias3[tn] = W[O_PE3B + tn * 16 + m];
    }
    int nval = NPTS - i0; if (nval > 256) nval = 256;
    int ntiles = (nval - w * 64 >= 64) ? 4 : 0;

#pragma unroll 1
    for (int tt = 0; tt < ntiles; ++tt) {
        int rbase = i0 + w * 64 + tt * 16;
        int arow = rbase + m;
        float4 c;
        c.x = rdf(pts_raw, (size_t)arow * 5 + 1, fp32);
        c.y = rdf(pts_raw, (size_t)arow * 5 + 2, fp32);
        c.z = rdf(pts_raw, (size_t)arow * 5 + 3, fp32);
        c.w = rdf(pts_raw, (size_t)arow * 5 + 4, fp32);
        union { unsigned u[4]; bf16x8_t v; } ah, al;
#pragma unroll
        for (int pp = 0; pp < 4; ++pp) {
            unsigned hu = 0, lu = 0;
#pragma unroll
            for (int s = 0; s < 2; ++s) {
                int j = 2 * pp + s;
                float h = b1[j];
                h = fmaf(c.x, w1[0 * 8 + j], h);
                h = fmaf(c.y, w1[1 * 8 + j], h);
                h = fmaf(c.z, w1[2 * 8 + j], h);
                h = fmaf(c.w, w1[3 * 8 + j], h);
                h = fmaxf(h, 0.f);
                unsigned short hi = f2us(h);
                unsigned short lo = f2us(h - us2f(hi));
                hu |= (unsigned)hi << (16 * s);
                lu |= (unsigned)lo << (16 * s);
            }
            ah.u[pp] = hu; al.u[pp] = lu;
        }
#pragma unroll
        for (int tn = 0; tn < 4; ++tn) {
            f32x4_t acc = {0.f, 0.f, 0.f, 0.f};
            acc = MFMA16(ah.v, b2h[tn], acc);
            acc = MFMA16(ah.v, b2l[tn], acc);
            acc = MFMA16(al.v, b2h[tn], acc);
#pragma unroll
            for (int e = 0; e < 4; ++e) {
                float v = fmaxf(acc[e] + bias2[tn], 0.f);
                unsigned short hi = f2us(v);
                hth[w][quad * 4 + e][tn * 16 + m] = hi;
                htl[w][quad * 4 + e][tn * 16 + m] = f2us(v - us2f(hi));
            }
        }
        bf16x8_t x0h = *(const bf16x8_t*)&hth[w][m][quad * 8];
        bf16x8_t x1h = *(const bf16x8_t*)&hth[w][m][32 + quad * 8];
        bf16x8_t x0l = *(const bf16x8_t*)&htl[w][m][quad * 8];
        bf16x8_t x1l = *(const bf16x8_t*)&htl[w][m][32 + quad * 8];
#pragma unroll
        for (int tn = 0; tn < 2; ++tn) {
            f32x4_t acc = {0.f, 0.f, 0.f, 0.f};
            acc = MFMA16(x0h, b3h[tn][0], acc);
            acc = MFMA16(x1h, b3h[tn][1], acc);
            acc = MFMA16(x0h, b3l[tn][0], acc);
            acc = MFMA16(x1h, b3l[tn][1], acc);
            acc = MFMA16(x0l, b3h[tn][0], acc);
            acc = MFMA16(x1l, b3h[tn][1], acc);
#pragma unroll
            for (int e = 0; e < 4; ++e)
                pt[w][quad * 4 + e][tn * 16 + m] = f2us(fmaxf(acc[e] + bias3[tn], 0.f));
        }
        uint4 q = *(const uint4*)&pt[w][m][quad * 8];
        pf_q[(size_t)arow * 4 + quad] = q;
    }

    int i = i0 + t;
    bool valid = t < nval;
    int b = 0, rk = 0;
    if (valid) {
        b = (int)rdf(pts_raw, (size_t)i * 5, fp32);
        bidN[i] = b;
        int v = i64 ? (int)((const long long*)pv_raw)[i] : ((const int*)pv_raw)[i];
        pvN[i] = v;
        rk = atomicAdd(&cnt[v], 1);
    }
    __shared__ int sb0, sflag;
    if (t == 0) { sb0 = b; sflag = 1; }
    __syncthreads();
    if (valid && b != sb0) sflag = 0;
    __syncthreads();
    if (sflag) {
        if (t == 0) atomicAdd(&bcnt[sb0], (float)nval);
    } else if (valid) {
        atomicAdd(&bcnt[b], 1.f);
    }
    if (valid) rank[i] = rk;
}

__global__ __launch_bounds__(256) void k_scat(const int* __restrict__ pv,
                                              const int* __restrict__ rank,
                                              const int* __restrict__ offs,
                                              const uint4* __restrict__ pf_q,
                                              uint4* __restrict__ pf_s) {
    int tid = blockIdx.x * 256 + threadIdx.x;
    int i = tid >> 2, quad = tid & 3;
    if (i >= NPTS) return;
    int sp = offs[pv[i]] + rank[i];
    pf_s[(size_t)sp * 4 + quad] = pf_q[(size_t)i * 4 + quad];
}

__global__ __launch_bounds__(256) void k_voxmlp(const int* __restrict__ offs, const int* __restrict__ cnt,
                                                const uint4* __restrict__ pf_s,
                                                const float* __restrict__ W,
                                                const void* __restrict__ pts_raw,
                                                unsigned* __restrict__ vf_u,
                                                void* __restrict__ outbase) {
    int v = blockIdx.x * 256 + threadIdx.x;
    if (v >= NVOX) return;
    int of32 = detect_fp32(pts_raw);
    float mx[32];
#pragma unroll
    for (int c = 0; c < 32; ++c) mx[c] = 0.f;
    int s = offs[v], n = cnt[v];
    for (int p = 0; p < n; ++p) {
        size_t base = (size_t)(s + p) * 4;
#pragma unroll
        for (int t = 0; t < 4; ++t) {
            uint4 q = pf_s[base + t];
            float a, b;
            unpack2(q.x, a, b); mx[8*t+0] = fmaxf(mx[8*t+0], a); mx[8*t+1] = fmaxf(mx[8*t+1], b);
            unpack2(q.y, a, b); mx[8*t+2] = fmaxf(mx[8*t+2], a); mx[8*t+3] = fmaxf(mx[8*t+3], b);
            unpack2(q.z, a, b); mx[8*t+4] = fmaxf(mx[8*t+4], a); mx[8*t+5] = fmaxf(mx[8*t+5], b);
            unpack2(q.w, a, b); mx[8*t+6] = fmaxf(mx[8*t+6], a); mx[8*t+7] = fmaxf(mx[8*t+7], b);
        }
    }
    float v1[32], vf[32], a1[32], o[20];
    dense<32, 32, true, true>(mx, v1, W + O_VE1W, W + O_VE1B);
    dense<32, 32, true, true>(v1, vf, W + O_VE2W, W + O_VE2B);
#pragma unroll
    for (int c = 0; c < 16; ++c) vf_u[(size_t)v * 16 + c] = pack2(vf[2*c], vf[2*c+1]);
    dense<32, 32, true, true>(v1, a1, W + O_AUX1W, W + O_AUX1B);
    dense<32, 20, false, false>(a1, o, W + O_AUX2W, nullptr);
    if (of32) {
        float* auxf = (float*)outbase + (size_t)NPTS * NCLS + (size_t)v * NCLS;
#pragma unroll
        for (int t = 0; t < NCLS; ++t) auxf[t] = o[t];
    } else {
        unsigned* auxu = (unsigned*)((bf16*)outbase + (size_t)NPTS * NCLS);
#pragma unroll
        for (int t = 0; t < 10; ++t) auxu[(size_t)v * 10 + t] = pack2(o[2*t], o[2*t+1]);
    }
}

__global__ __launch_bounds__(256) void k3_mfma(const int* __restrict__ bid, const int* __restrict__ pv,
                                               const uint4* __restrict__ pf_q,
                                               const uint4* __restrict__ vf_q,
                                               const float* __restrict__ W,
                                               const unsigned short* __restrict__ WTfu,
                                               float* __restrict__ bsum8) {
    __shared__ int sbid[256];
    __shared__ float red[4][64];
    __shared__ int sflag;
    int t = threadIdx.x;
    int i0 = blockIdx.x * 256;
    int nval = NPTS - i0; if (nval > 256) nval = 256;
    if (t < nval) sbid[t] = bid[i0 + t];
    if (t == 0) sflag = (bid[i0] == bid[i0 + nval - 1]) ? 1 : 0;

    int lane = t & 63, w = t >> 6;
    int m = lane & 15, quad = lane >> 4;
    bf16x8_t bw0[4], bw1[4];
    float bias[4];
#pragma unroll
    for (int tn = 0; tn < 4; ++tn) {
        bw0[tn] = *(const bf16x8_t*)(WTfu + (tn * 16 + m) * 64 + quad * 8);
        bw1[tn] = *(const bf16x8_t*)(WTfu + (tn * 16 + m) * 64 + 32 + quad * 8);
        bias[tn] = W[O_FUB + tn * 16 + m];
    }
    __syncthreads();
    int uni = sflag;
    int b0 = sbid[0];
    int rep = (blockIdx.x & 7) * 256;
    int ntiles = (nval - w * 64 >= 64) ? 4 : 0;

    float csum[4] = {0.f, 0.f, 0.f, 0.f};
#pragma unroll
    for (int tt = 0; tt < 4; ++tt) {
        if (tt >= ntiles) break;
        int rbase = i0 + w * 64 + tt * 16;
        int arow = rbase + m;
        int pvr = pv[arow];
        uint4 va = vf_q[(size_t)pvr * 4 + quad];
        uint4 vb = pf_q[(size_t)arow * 4 + quad];
        bf16x8_t a0 = *(bf16x8_t*)&va;
        bf16x8_t a1 = *(bf16x8_t*)&vb;
        float f[4][4];
#pragma unroll
        for (int tn = 0; tn < 4; ++tn) {
            f32x4_t acc = {0.f, 0.f, 0.f, 0.f};
            acc = MFMA16(a0, bw0[tn], acc);
            acc = MFMA16(a1, bw1[tn], acc);
#pragma unroll
            for (int e = 0; e < 4; ++e) f[tn][e] = fmaxf(acc[e] + bias[tn], 0.f);
        }
        if (uni) {
#pragma unroll
            for (int tn = 0; tn < 4; ++tn) {
                float s = f[tn][0] + f[tn][1] + f[tn][2] + f[tn][3];
                s += __shfl_xor(s, 16);
                s += __shfl_xor(s, 32);
                csum[tn] += s;
            }
        } else {
#pragma unroll
            for (int tn = 0; tn < 4; ++tn)
#pragma unroll
                for (int e = 0; e < 4; ++e)
                    atomicAdd(&bsum8[rep + sbid[rbase - i0 + quad * 4 + e] * 64 + tn * 16 + m], f[tn][e]);
        }
    }
    if (uni) {
        float mine = quad == 0 ? csum[0] : quad == 1 ? csum[1] : quad == 2 ? csum[2] : csum[3];
        red[w][quad * 16 + m] = mine;
        __syncthreads();
        if (t < 64) {
            float s = red[0][t] + red[1][t] + red[2][t] + red[3][t];
            atomicAdd(&bsum8[rep + b0 * 64 + t], s);
        }
    }
}

__global__ void k4_gate(const float* __restrict__ bsum8, const float* __restrict__ bcnt,
                        const float* __restrict__ W, float* __restrict__ gate) {
    __shared__ float m[4][64];
    __shared__ float hid[4][4];
    int tid = threadIdx.x, b = tid >> 6, c = tid & 63;
    float s = 0.f;
#pragma unroll
    for (int r = 0; r < 8; ++r) s += bsum8[r * 256 + tid];
    m[b][c] = s / fmaxf(bcnt[b], 1.f);
    __syncthreads();
    if (c < 4) {
        const float* w = W + O_SE1W;
        float a = (W + O_SE1B)[c];
        for (int k = 0; k < 64; ++k) a = fmaf(m[b][k], w[k * 4 + c], a);
        hid[b][c] = fmaxf(a, 0.f);
    }
    __syncthreads();
    const float* w2 = W + O_SE2W;
    float g = (W + O_SE2B)[c];
#pragma unroll
    for (int h = 0; h < 4; ++h) g = fmaf(hid[b][h], w2[h * 64 + c], g);
    gate[tid] = 1.f + 1.f / (1.f + expf(-g));
}

__global__ __launch_bounds__(256) void k5_mfma(const int* __restrict__ bid, const int* __restrict__ pv,
                                               const uint4* __restrict__ pf_q,
                                               const uint4* __restrict__ vf_q,
                                               const float* __restrict__ W,
                                               const unsigned short* __restrict__ WTfu,
                                               const unsigned short* __restrict__ WTc1,
                                               const unsigned short* __restrict__ WTc2,
                                               const float* __restrict__ gate,
                                               const void* __restrict__ pts_raw,
                                               void* __restrict__ out) {
    __shared__ float sg[256];
    __shared__ int sbid[256];
    __shared__ int sflag;
    __shared__ __align__(16) unsigned short ft[4][16][72];
    __shared__ __align__(16) unsigned short ht[4][16][40];
    __shared__ float ot[4][16][20];
    int t = threadIdx.x;
    int i0 = blockIdx.x * 256;
    int nval = NPTS - i0; if (nval > 256) nval = 256;
    sg[t] = gate[t];
    if (t < nval) sbid[t] = bid[i0 + t];
    if (t == 0) sflag = (bid[i0] == bid[i0 + nval - 1]) ? 1 : 0;

    int lane = t & 63, w = t >> 6;
    int m = lane & 15, quad = lane >> 4;
    bf16x8_t bfu0[4], bfu1[4], bc10[2], bc11[2], bc2[2];
    float biasfu[4], biasc1[2];
#pragma unroll
    for (int tn = 0; tn < 4; ++tn) {
        bfu0[tn] = *(const bf16x8_t*)(WTfu + (tn * 16 + m) * 64 + quad * 8);
        bfu1[tn] = *(const bf16x8_t*)(WTfu + (tn * 16 + m) * 64 + 32 + quad * 8);
        biasfu[tn] = W[O_FUB + tn * 16 + m];
    }
#pragma unroll
    for (int tn = 0; tn < 2; ++tn) {
        bc10[tn] = *(const bf16x8_t*)(WTc1 + (tn * 16 + m) * 64 + quad * 8);
        bc11[tn] = *(const bf16x8_t*)(WTc1 + (tn * 16 + m) * 64 + 32 + quad * 8);
        bc2[tn]  = *(const bf16x8_t*)(WTc2 + (tn * 16 + m) * 32 + quad * 8);
        biasc1[tn] = W[O_CLS1B + tn * 16 + m];
    }
    __syncthreads();
    int uni = sflag;
    int of32 = detect_fp32(pts_raw);
    int ntiles = (nval - w * 64 >= 64) ? 4 : 0;

#pragma unroll 1
    for (int tt = 0; tt < ntiles; ++tt) {
        int rbase = i0 + w * 64 + tt * 16;
        int arow = rbase + m;
        int pvr = pv[arow];
        uint4 va = vf_q[(size_t)pvr * 4 + quad];
        uint4 vb = pf_q[(size_t)arow * 4 + quad];
        bf16x8_t a0 = *(bf16x8_t*)&va;
        bf16x8_t a1 = *(bf16x8_t*)&vb;
        float gcol[4];
        if (uni) {
#pragma unroll
            for (int tn = 0; tn < 4; ++tn) gcol[tn] = sg[sbid[0] * 64 + tn * 16 + m];
        }
#pragma unroll
        for (int tn = 0; tn < 4; ++tn) {
            f32x4_t acc = {0.f, 0.f, 0.f, 0.f};
            acc = MFMA16(a0, bfu0[tn], acc);
            acc = MFMA16(a1, bfu1[tn], acc);
#pragma unroll
            for (int e = 0; e < 4; ++e) {
                float fv = fmaxf(acc[e] + biasfu[tn], 0.f);
                float g = uni ? gcol[tn] : sg[sbid[rbase - i0 + quad * 4 + e] * 64 + tn * 16 + m];
                ft[w][quad * 4 + e][tn * 16 + m] = f2us(fv * g);
            }
        }
        bf16x8_t c0 = *(const bf16x8_t*)&ft[w][m][quad * 8];
        bf16x8_t c1 = *(const bf16x8_t*)&ft[w][m][32 + quad * 8];
#pragma unroll
        for (int tn = 0; tn < 2; ++tn) {
            f32x4_t acc = {0.f, 0.f, 0.f, 0.f};
            acc = MFMA16(c0, bc10[tn], acc);
            acc = MFMA16(c1, bc11[tn], acc);
#pragma unroll
            for (int e = 0; e < 4; ++e)
                ht[w][quad * 4 + e][tn * 16 + m] = f2us(fmaxf(acc[e] + biasc1[tn], 0.f));
        }
        bf16x8_t d0 = *(const bf16x8_t*)&ht[w][m][quad * 8];
#pragma unroll
        for (int tn = 0; tn < 2; ++tn) {
            f32x4_t acc = {0.f, 0.f, 0.f, 0.f};
            acc = MFMA16(d0, bc2[tn], acc);
            int c = tn * 16 + m;
            if (c < NCLS) {
#pragma unroll
                for (int e = 0; e < 4; ++e) ot[w][quad * 4 + e][c] = acc[e];
            }
        }
        if (of32) {
            float* of = (float*)out + (size_t)rbase * NCLS;
#pragma unroll
            for (int k = 0; k < 5; ++k) {
                int idx = k * 64 + lane;
                of[idx] = ((const float*)ot[w])[idx];
            }
        } else {
            unsigned* ow = (unsigned*)((unsigned short*)out + (size_t)rbase * NCLS);
#pragma unroll
            for (int k = 0; k < 3; ++k) {
                int idx = k * 64 + lane;
                if (idx < 160) {
                    int p = idx / 10, c2 = idx - p * 10;
                    ow[idx] = pack2(ot[w][p][2 * c2], ot[w][p][2 * c2 + 1]);
                }
            }
        }
    }
}

extern "C" void kernel_launch(void* const* d_in, const int* in_sizes, int n_in,
                              void* d_out, int out_size, void* d_ws, size_t ws_size,
                              hipStream_t stream) {
    static MegaArgs ma;
    ma.p.pe_w1 = d_in[2];  ma.p.pe_g1 = d_in[3];  ma.p.pe_b1 = d_in[4];
    ma.p.pe_w2 = d_in[5];  ma.p.pe_g2 = d_in[6];  ma.p.pe_b2 = d_in[7];
    ma.p.pe_w3 = d_in[8];  ma.p.pe_g3 = d_in[9];  ma.p.pe_b3 = d_in[10];
    ma.p.ve_w1 = d_in[11]; ma.p.ve_g1 = d_in[12]; ma.p.ve_b1 = d_in[13];
    ma.p.ve_w2 = d_in[14]; ma.p.ve_g2 = d_in[15]; ma.p.ve_b2 = d_in[16];
    ma.p.fu_w  = d_in[17]; ma.p.fu_g  = d_in[18]; ma.p.fu_b  = d_in[19];
    ma.p.se_w1 = d_in[20]; ma.p.se_b1 = d_in[21];
    ma.p.se_w2 = d_in[22]; ma.p.se_b2 = d_in[23];
    ma.p.cls_w1 = d_in[24]; ma.p.cls_g1 = d_in[25]; ma.p.cls_b1 = d_in[26];
    ma.p.cls_w2 = d_in[27];
    ma.p.aux_w1 = d_in[28]; ma.p.aux_g1 = d_in[29]; ma.p.aux_b1 = d_in[30];
    ma.p.aux_w2 = d_in[31];

    float* base = (float*)d_ws;
    ma.pts_raw = d_in[0];
    ma.pv_raw  = d_in[1];
    ma.pvN  = (int*)(base + L_PV);
    ma.bidN = (int*)(base + L_BID);
    ma.cnt  = (int*)(base + L_CNT);
    ma.bsum8 = base + L_BSUM;
    ma.bcnt = base + L_BCNT;
    ma.gate = base + L_GATE;
    ma.offs = (int*)(base + L_OFFS);
    ma.bs1  = (int*)(base + L_BS1);
    ma.bb   = (int*)(base + L_BB);
    ma.rank = (int*)(base + L_IDX);
    ma.W    = base + L_W;
    ma.WT   = (unsigned short*)(base + L_WT);
    ma.vf_u = (unsigned*)(base + L_VFU);
    ma.pf_q = (uint4*)(base + L_PFQ);
    ma.pf_s = (uint4*)(base + L_PFS);
    ma.out  = d_out;

    // zero cnt + bsum8 + bcnt (contiguous)
    hipMemsetAsync(ma.cnt, 0, (NVOX + 2048 + 4) * sizeof(float), stream);

    // ---- preferred: cooperative mega kernel, grid sized by the runtime's own occupancy calc ----
    hipError_t lerr = hipErrorUnknown;
    int nb = 0;
    if (hipOccupancyMaxActiveBlocksPerMultiprocessor(&nb, k_mega, 256, 0) == hipSuccess && nb > 0) {
        int grid = nb * 256;              // 256 CUs on MI355X
        if (grid > 1024) grid = 1024;
        void* params[] = { (void*)&ma };
        lerr = hipLaunchCooperativeKernel((void*)k_mega, dim3(grid), dim3(256), params, 0, stream);
    }
    if (lerr != hipSuccess) {
        // ---- fallback: round-5 multi-kernel chain (known-passing) ----
        constexpr int NBV = (NVOX + 255) / 256;
        constexpr int NBSC = (NPTS * 4 + 255) / 256;
        unsigned short* wtfu = ma.WT + WT_FU;
        unsigned short* wtc1 = ma.WT + WT_C1;
        unsigned short* wtc2 = ma.WT + WT_C2;
        unsigned short* wt2h = ma.WT + WT_2H;
        unsigned short* wt2l = ma.WT + WT_2L;
        unsigned short* wt3h = ma.WT + WT_3H;
        unsigned short* wt3l = ma.WT + WT_3L;
        k0_prep<<<1, 256, 0, stream>>>(ma.p, ma.pts_raw, ma.W, ma.WT);
        k1_fused<<<NBM, 256, 0, stream>>>(ma.pts_raw, ma.pv_raw, ma.W, wt2h, wt2l, wt3h, wt3l,
                                          ma.pvN, ma.bidN, ma.cnt, ma.bcnt, ma.rank, ma.pf_q);
        k_scan1<<<NBS, 256, 0, stream>>>(ma.cnt, ma.bs1);
        k_scan2<<<1, 256, 0, stream>>>(ma.bs1, ma.bb, NBS);
        k_scan3<<<NBS, 256, 0, stream>>>(ma.cnt, ma.bb, ma.offs);
        k_scat<<<NBSC, 256, 0, stream>>>(ma.pvN, ma.rank, ma.offs, ma.pf_q, ma.pf_s);
        k_voxmlp<<<NBV, 256, 0, stream>>>(ma.offs, ma.cnt, ma.pf_s, ma.W, ma.pts_raw, ma.vf_u, d_out);
        k3_mfma<<<NBM, 256, 0, stream>>>(ma.bidN, ma.pvN, ma.pf_q, (const uint4*)ma.vf_u, ma.W, wtfu, ma.bsum8);
        k4_gate<<<1, 256, 0, stream>>>(ma.bsum8, ma.bcnt, ma.W, ma.gate);
        k5_mfma<<<NBM, 256, 0, stream>>>(ma.bidN, ma.pvN, ma.pf_q, (const uint4*)ma.vf_u, ma.W,
                                         wtfu, wtc1, wtc2, ma.gate, ma.pts_raw, d_out);
    }
}

// Round 8
// 553.938 us; speedup vs baseline: 2.3794x; 2.3794x over previous
//
#include <hip/hip_runtime.h>
#include <hip/hip_bf16.h>

#define NPTS 1000000
#define NVOX 200000
#define NCLS 20

typedef __hip_bfloat16 bf16;
typedef __attribute__((ext_vector_type(8))) short bf16x8_t;
typedef __attribute__((ext_vector_type(4))) float f32x4_t;
#define MFMA16(a, b, c) __builtin_amdgcn_mfma_f32_16x16x32_bf16(a, b, c, 0, 0, 0)

// ---------- workspace layout (fp32 words) ----------
constexpr size_t L_PTSC = 0;                          // (unused; retained layout)
constexpr size_t L_PV   = L_PTSC + (size_t)NPTS * 4;  // N int32 voxel ids
constexpr size_t L_BID  = L_PV + NPTS;                // N int32 batch ids
constexpr size_t L_CNT  = L_BID + NPTS;               // V counts (zero)
constexpr size_t L_BSUM = L_CNT + NVOX;               // 8 x 256 replicated (zero)
constexpr size_t L_BCNT = L_BSUM + 2048;              // 4 (zero)
constexpr size_t L_GATE = L_BCNT + 4;                 // 256
constexpr size_t L_FLAG = L_GATE + 256;               // 4 (unused)
constexpr size_t L_OFFS = L_FLAG + 4;                 // V
constexpr size_t L_OFFW = L_OFFS + NVOX;              // V (unused)
constexpr size_t L_BS1  = L_OFFW + NVOX;              // 256 block sums
constexpr size_t L_BB   = L_BS1 + 256;                // 256 block bases
constexpr size_t L_IDX  = L_BB + 256;                 // N rank (within-voxel arrival order)
constexpr size_t L_W    = L_IDX + NPTS;               // folded weights fp32
// weight offsets inside W
constexpr int O_PE1W = 0;      constexpr int O_PE1B = 128;
constexpr int O_PE2W = 160;    constexpr int O_PE2B = 2208;
constexpr int O_PE3W = 2272;   constexpr int O_PE3B = 4320;
constexpr int O_VE1W = 4352;   constexpr int O_VE1B = 5376;
constexpr int O_VE2W = 5408;   constexpr int O_VE2B = 6432;
constexpr int O_FUW  = 6464;   constexpr int O_FUB  = 10560;
constexpr int O_SE1W = 10624;  constexpr int O_SE1B = 10880;
constexpr int O_SE2W = 10884;  constexpr int O_SE2B = 11140;
constexpr int O_CLS1W = 11204; constexpr int O_CLS1B = 13252;
constexpr int O_CLS2W = 13284;
constexpr int O_AUX1W = 13924; constexpr int O_AUX1B = 14948;
constexpr int O_AUX2W = 14980;
constexpr int W_TOTAL = 15620;
constexpr size_t L_WT  = L_W + W_TOTAL;               // bf16 transposed weights
static_assert((L_WT * 4) % 16 == 0, "WT alignment");
// WT sub-offsets in u16 units
constexpr int WT_FU = 0;          // [64][64]
constexpr int WT_C1 = 4096;       // [32][64]
constexpr int WT_C2 = 6144;       // [32][32]
constexpr int WT_2H = 7168;       // pe2 [64 n][32 k] hi
constexpr int WT_2L = 9216;       // pe2 lo
constexpr int WT_3H = 11264;      // pe3 [32 n][64 k] hi
constexpr int WT_3L = 13312;      // pe3 lo
constexpr int WT_C1B = 15360;     // 4 batch-scaled copies of C1 (gate folded), [b][32n][64k]
constexpr int WT_U16 = 15360 + 8192;
constexpr size_t L_VFU = L_WT + WT_U16 / 2;
constexpr size_t L_PFQ = L_VFU + (size_t)NVOX * 16;   // N*16 packed bf16 pairs (orig order)
constexpr size_t L_PFS = L_PFQ + (size_t)NPTS * 16;   // N*16 packed bf16 pairs (sorted order)
static_assert((L_VFU * 4) % 16 == 0, "vf alignment");
static_assert((L_PFQ * 4) % 16 == 0, "pf alignment");
static_assert((L_PFS * 4) % 16 == 0, "pfs alignment");

static __device__ __forceinline__ float b2f(bf16 v) { return __bfloat162float(v); }
static __device__ __forceinline__ float us2f(unsigned short u) { return __uint_as_float((unsigned)u << 16); }
static __device__ __forceinline__ unsigned short f2us(float f) {
    unsigned u = __float_as_uint(f);
    u += 0x7fffu + ((u >> 16) & 1u);
    return (unsigned short)(u >> 16);
}
static __device__ __forceinline__ unsigned pack2(float a, float b) {
    return (unsigned)f2us(a) | ((unsigned)f2us(b) << 16);
}
static __device__ __forceinline__ void unpack2(unsigned u, float& a, float& b) {
    a = __uint_as_float(u << 16);
    b = __uint_as_float(u & 0xffff0000u);
}
static __device__ __forceinline__ float rdf(const void* p, size_t idx, int fp32) {
    return fp32 ? ((const float*)p)[idx] : b2f(((const bf16*)p)[idx]);
}
// dtype self-detection
static __device__ __forceinline__ int detect_fp32(const void* pts_raw) {
    const unsigned short* ptsu = (const unsigned short*)pts_raw;
    return (ptsu[1] == 0 && ptsu[11] == 0) ? 1 : 0;
}
static __device__ __forceinline__ int detect_i64(const void* pv_raw) {
    const unsigned* pvu = (const unsigned*)pv_raw;
    return (pvu[1] == 0 && pvu[3] == 0 && pvu[5] == 0 && pvu[7] == 0) ? 1 : 0;
}

template <int K, int M, bool RELU, bool BIAS>
static __device__ __forceinline__ void dense(const float* __restrict__ x, float* __restrict__ y,
                                             const float* __restrict__ w, const float* __restrict__ b) {
#pragma unroll
    for (int j = 0; j < M; ++j) {
        float a = BIAS ? b[j] : 0.f;
#pragma unroll
        for (int k = 0; k < K; ++k) a = fmaf(x[k], w[k * M + j], a);
        y[j] = RELU ? fmaxf(a, 0.f) : a;
    }
}

static __device__ __forceinline__ int block_excl_scan(int v, int t) {
    __shared__ int sh[2][256];
    int cur = 0;
    sh[0][t] = v; __syncthreads();
#pragma unroll
    for (int off = 1; off < 256; off <<= 1) {
        int val = sh[cur][t];
        if (t >= off) val += sh[cur][t - off];
        sh[cur ^ 1][t] = val; __syncthreads();
        cur ^= 1;
    }
    return sh[cur][t] - v;
}

// ---------- K0c: fold BN into weights + build bf16 transposed weights ----------
struct WPtrs {
    const void *pe_w1, *pe_g1, *pe_b1, *pe_w2, *pe_g2, *pe_b2, *pe_w3, *pe_g3, *pe_b3;
    const void *ve_w1, *ve_g1, *ve_b1, *ve_w2, *ve_g2, *ve_b2;
    const void *fu_w, *fu_g, *fu_b;
    const void *se_w1, *se_b1, *se_w2, *se_b2;
    const void *cls_w1, *cls_g1, *cls_b1, *cls_w2;
    const void *aux_w1, *aux_g1, *aux_b1, *aux_w2;
};

static __device__ void foldw(float* d, const void* w, const void* g, int K, int M, int fp32) {
    const float INV = 0.9999950000374997f;  // 1/sqrt(1+1e-5)
    for (int idx = threadIdx.x; idx < K * M; idx += 256)
        d[idx] = rdf(w, idx, fp32) * (rdf(g, idx % M, fp32) * INV);
}
static __device__ void cpv(float* d, const void* s, int n, int fp32) {
    for (int idx = threadIdx.x; idx < n; idx += 256) d[idx] = rdf(s, idx, fp32);
}

__global__ void k0_prep(WPtrs p, const void* __restrict__ pts_raw, float* __restrict__ W,
                        unsigned short* __restrict__ WT) {
    int f = detect_fp32(pts_raw);
    foldw(W + O_PE1W, p.pe_w1, p.pe_g1, 4, 32, f);   cpv(W + O_PE1B, p.pe_b1, 32, f);
    foldw(W + O_PE2W, p.pe_w2, p.pe_g2, 32, 64, f);  cpv(W + O_PE2B, p.pe_b2, 64, f);
    foldw(W + O_PE3W, p.pe_w3, p.pe_g3, 64, 32, f);  cpv(W + O_PE3B, p.pe_b3, 32, f);
    foldw(W + O_VE1W, p.ve_w1, p.ve_g1, 32, 32, f);  cpv(W + O_VE1B, p.ve_b1, 32, f);
    foldw(W + O_VE2W, p.ve_w2, p.ve_g2, 32, 32, f);  cpv(W + O_VE2B, p.ve_b2, 32, f);
    foldw(W + O_FUW,  p.fu_w,  p.fu_g,  64, 64, f);  cpv(W + O_FUB,  p.fu_b, 64, f);
    cpv(W + O_SE1W, p.se_w1, 256, f);  cpv(W + O_SE1B, p.se_b1, 4, f);
    cpv(W + O_SE2W, p.se_w2, 256, f);  cpv(W + O_SE2B, p.se_b2, 64, f);
    foldw(W + O_CLS1W, p.cls_w1, p.cls_g1, 64, 32, f); cpv(W + O_CLS1B, p.cls_b1, 32, f);
    cpv(W + O_CLS2W, p.cls_w2, 640, f);
    foldw(W + O_AUX1W, p.aux_w1, p.aux_g1, 32, 32, f); cpv(W + O_AUX1B, p.aux_b1, 32, f);
    cpv(W + O_AUX2W, p.aux_w2, 640, f);
    __syncthreads();
    unsigned short* wtfu = WT + WT_FU;          // [64][64]
    unsigned short* wtc1 = WT + WT_C1;          // [32][64]
    unsigned short* wtc2 = WT + WT_C2;          // [32][32], rows >= 20 zero
    unsigned short* wt2h = WT + WT_2H;          // [64 n][32 k]
    unsigned short* wt2l = WT + WT_2L;
    unsigned short* wt3h = WT + WT_3H;          // [32 n][64 k]
    unsigned short* wt3l = WT + WT_3L;
    for (int idx = threadIdx.x; idx < 4096; idx += 256) {
        int n = idx >> 6, k = idx & 63;
        wtfu[idx] = f2us(W[O_FUW + k * 64 + n]);
    }
    for (int idx = threadIdx.x; idx < 2048; idx += 256) {
        int n = idx >> 6, k = idx & 63;
        wtc1[idx] = f2us(W[O_CLS1W + k * 32 + n]);
    }
    for (int idx = threadIdx.x; idx < 1024; idx += 256) {
        int n = idx >> 5, k = idx & 31;
        wtc2[idx] = (n < NCLS) ? f2us(W[O_CLS2W + k * NCLS + n]) : (unsigned short)0;
    }
    // split-precision (hi + residual lo) transposed weights for the point MLP MFMA
    for (int idx = threadIdx.x; idx < 2048; idx += 256) {
        int n = idx >> 5, k = idx & 31;
        float v = W[O_PE2W + k * 64 + n];
        unsigned short hi = f2us(v);
        wt2h[idx] = hi;
        wt2l[idx] = f2us(v - us2f(hi));
    }
    for (int idx = threadIdx.x; idx < 2048; idx += 256) {
        int n = idx >> 6, k = idx & 63;
        float v = W[O_PE3W + k * 32 + n];
        unsigned short hi = f2us(v);
        wt3h[idx] = hi;
        wt3l[idx] = f2us(v - us2f(hi));
    }
}

// ---------- counting-sort scan ----------
__global__ __launch_bounds__(256) void k_scan1(const int* __restrict__ cnt, int* __restrict__ bs) {
    int t = threadIdx.x;
    int base = blockIdx.x * 1024 + t * 4;
    int s = 0;
#pragma unroll
    for (int k = 0; k < 4; ++k) { int idx = base + k; if (idx < NVOX) s += cnt[idx]; }
    __shared__ int red[256];
    red[t] = s; __syncthreads();
    for (int off = 128; off > 0; off >>= 1) { if (t < off) red[t] += red[t + off]; __syncthreads(); }
    if (t == 0) bs[blockIdx.x] = red[0];
}

__global__ __launch_bounds__(256) void k_scan2(const int* __restrict__ bs, int* __restrict__ bb, int nb) {
    int t = threadIdx.x;
    int v = (t < nb) ? bs[t] : 0;
    int e = block_excl_scan(v, t);
    bb[t] = e;
}

__global__ __launch_bounds__(256) void k_scan3(const int* __restrict__ cnt, const int* __restrict__ bb,
                                               int* __restrict__ offs) {
    int t = threadIdx.x;
    int base = blockIdx.x * 1024 + t * 4;
    int c[4]; int s = 0;
#pragma unroll
    for (int k = 0; k < 4; ++k) { int idx = base + k; c[k] = (idx < NVOX) ? cnt[idx] : 0; s += c[k]; }
    int run = bb[blockIdx.x] + block_excl_scan(s, t);
#pragma unroll
    for (int k = 0; k < 4; ++k) {
        int idx = base + k;
        if (idx < NVOX) { offs[idx] = run; run += c[k]; }
    }
}

// ---------- K1 (fused): point MLP via MFMA + normalize/histogram tail ----------
__global__ __launch_bounds__(256) void k1_fused(const void* __restrict__ pts_raw,
                                                const void* __restrict__ pv_raw,
                                                const float* __restrict__ W,
                                                const unsigned short* __restrict__ WT2H,
                                                const unsigned short* __restrict__ WT2L,
                                                const unsigned short* __restrict__ WT3H,
                                                const unsigned short* __restrict__ WT3L,
                                                int* __restrict__ pvN,
                                                int* __restrict__ bidN,
                                                int* __restrict__ cnt,
                                                float* __restrict__ bcnt,
                                                int* __restrict__ rank,
                                                uint4* __restrict__ pf_q) {
    __shared__ __align__(16) unsigned short hth[4][16][72];  // h2 hi, per wave
    __shared__ __align__(16) unsigned short htl[4][16][72];  // h2 lo
    __shared__ __align__(16) unsigned short pt[4][16][40];   // pf bf16 staging
    int t = threadIdx.x;
    int lane = t & 63, w = t >> 6;
    int m = lane & 15, quad = lane >> 4;
    int i0 = blockIdx.x * 256;
    int fp32 = detect_fp32(pts_raw), i64 = detect_i64(pv_raw);

    float w1[32], b1[8];
#pragma unroll
    for (int k = 0; k < 4; ++k)
#pragma unroll
        for (int j = 0; j < 8; ++j) w1[k * 8 + j] = W[O_PE1W + k * 32 + quad * 8 + j];
#pragma unroll
    for (int j = 0; j < 8; ++j) b1[j] = W[O_PE1B + quad * 8 + j];
    bf16x8_t b2h[4], b2l[4], b3h[2][2], b3l[2][2];
    float bias2[4], bias3[2];
#pragma unroll
    for (int tn = 0; tn < 4; ++tn) {
        b2h[tn] = *(const bf16x8_t*)(WT2H + (tn * 16 + m) * 32 + quad * 8);
        b2l[tn] = *(const bf16x8_t*)(WT2L + (tn * 16 + m) * 32 + quad * 8);
        bias2[tn] = W[O_PE2B + tn * 16 + m];
    }
#pragma unroll
    for (int tn = 0; tn < 2; ++tn) {
#pragma unroll
        for (int kh = 0; kh < 2; ++kh) {
            b3h[tn][kh] = *(const bf16x8_t*)(WT3H + (tn * 16 + m) * 64 + kh * 32 + quad * 8);
            b3l[tn][kh] = *(const bf16x8_t*)(WT3L + (tn * 16 + m) * 64 + kh * 32 + quad * 8);
        }
        bias3[tn] = W[O_PE3B + tn * 16 + m];
    }
    int nval = NPTS - i0; if (nval > 256) nval = 256;
    int ntiles = (nval - w * 64 >= 64) ? 4 : 0;

#pragma unroll 1
    for (int tt = 0; tt < ntiles; ++tt) {
        int rbase = i0 + w * 64 + tt * 16;
        int arow = rbase + m;
        float4 c;
        c.x = rdf(pts_raw, (size_t)arow * 5 + 1, fp32);
        c.y = rdf(pts_raw, (size_t)arow * 5 + 2, fp32);
        c.z = rdf(pts_raw, (size_t)arow * 5 + 3, fp32);
        c.w = rdf(pts_raw, (size_t)arow * 5 + 4, fp32);
        union { unsigned u[4]; bf16x8_t v; } ah, al;
#pragma unroll
        for (int pp = 0; pp < 4; ++pp) {
            unsigned hu = 0, lu = 0;
#pragma unroll
            for (int s = 0; s < 2; ++s) {
                int j = 2 * pp + s;
                float h = b1[j];
                h = fmaf(c.x, w1[0 * 8 + j], h);
                h = fmaf(c.y, w1[1 * 8 + j], h);
                h = fmaf(c.z, w1[2 * 8 + j], h);
                h = fmaf(c.w, w1[3 * 8 + j], h);
                h = fmaxf(h, 0.f);
                unsigned short hi = f2us(h);
                unsigned short lo = f2us(h - us2f(hi));
                hu |= (unsigned)hi << (16 * s);
                lu |= (unsigned)lo << (16 * s);
            }
            ah.u[pp] = hu; al.u[pp] = lu;
        }
#pragma unroll
        for (int tn = 0; tn < 4; ++tn) {
            f32x4_t acc = {0.f, 0.f, 0.f, 0.f};
            acc = MFMA16(ah.v, b2h[tn], acc);
            acc = MFMA16(ah.v, b2l[tn], acc);
            acc = MFMA16(al.v, b2h[tn], acc);
#pragma unroll
            for (int e = 0; e < 4; ++e) {
                float v = fmaxf(acc[e] + bias2[tn], 0.f);
                unsigned short hi = f2us(v);
                hth[w][quad * 4 + e][tn * 16 + m] = hi;
                htl[w][quad * 4 + e][tn * 16 + m] = f2us(v - us2f(hi));
            }
        }
        bf16x8_t x0h = *(const bf16x8_t*)&hth[w][m][quad * 8];
        bf16x8_t x1h = *(const bf16x8_t*)&hth[w][m][32 + quad * 8];
        bf16x8_t x0l = *(const bf16x8_t*)&htl[w][m][quad * 8];
        bf16x8_t x1l = *(const bf16x8_t*)&htl[w][m][32 + quad * 8];
#pragma unroll
        for (int tn = 0; tn < 2; ++tn) {
            f32x4_t acc = {0.f, 0.f, 0.f, 0.f};
            acc = MFMA16(x0h, b3h[tn][0], acc);
            acc = MFMA16(x1h, b3h[tn][1], acc);
            acc = MFMA16(x0h, b3l[tn][0], acc);
            acc = MFMA16(x1h, b3l[tn][1], acc);
            acc = MFMA16(x0l, b3h[tn][0], acc);
            acc = MFMA16(x1l, b3h[tn][1], acc);
#pragma unroll
            for (int e = 0; e < 4; ++e)
                pt[w][quad * 4 + e][tn * 16 + m] = f2us(fmaxf(acc[e] + bias3[tn], 0.f));
        }
        uint4 q = *(const uint4*)&pt[w][m][quad * 8];
        pf_q[(size_t)arow * 4 + quad] = q;
    }

    // ---- fused norm tail: ids + histogram atomic (rank) + batch counts ----
    int i = i0 + t;
    bool valid = t < nval;
    int b = 0, rk = 0;
    if (valid) {
        b = (int)rdf(pts_raw, (size_t)i * 5, fp32);
        bidN[i] = b;
        int v = i64 ? (int)((const long long*)pv_raw)[i] : ((const int*)pv_raw)[i];
        pvN[i] = v;
        rk = atomicAdd(&cnt[v], 1);
    }
    __shared__ int sb0, sflag;
    if (t == 0) { sb0 = b; sflag = 1; }
    __syncthreads();
    if (valid && b != sb0) sflag = 0;
    __syncthreads();
    if (sflag) {
        if (t == 0) atomicAdd(&bcnt[sb0], (float)nval);
    } else if (valid) {
        atomicAdd(&bcnt[b], 1.f);
    }
    if (valid) rank[i] = rk;
}

// ---------- K1b: pf scatter into voxel-sorted order ----------
__global__ __launch_bounds__(256) void k_scat(const int* __restrict__ pv,
                                              const int* __restrict__ rank,
                                              const int* __restrict__ offs,
                                              const uint4* __restrict__ pf_q,
                                              uint4* __restrict__ pf_s) {
    int tid = blockIdx.x * 256 + threadIdx.x;
    int i = tid >> 2, quad = tid & 3;
    if (i >= NPTS) return;
    int sp = offs[pv[i]] + rank[i];
    pf_s[(size_t)sp * 4 + quad] = pf_q[(size_t)i * 4 + quad];
}

// ---------- K2: per-voxel max (streaming reads of sorted pf) + voxel MLP + aux ----------
__global__ __launch_bounds__(256) void k_voxmlp(const int* __restrict__ offs, const int* __restrict__ cnt,
                                                const uint4* __restrict__ pf_s,
                                                const float* __restrict__ W,
                                                const void* __restrict__ pts_raw,
                                                unsigned* __restrict__ vf_u,
                                                void* __restrict__ outbase) {
    int v = blockIdx.x * 256 + threadIdx.x;
    if (v >= NVOX) return;
    int of32 = detect_fp32(pts_raw);
    float mx[32];
#pragma unroll
    for (int c = 0; c < 32; ++c) mx[c] = 0.f;
    int s = offs[v], n = cnt[v];
    for (int p = 0; p < n; ++p) {
        size_t base = (size_t)(s + p) * 4;
#pragma unroll
        for (int t = 0; t < 4; ++t) {
            uint4 q = pf_s[base + t];
            float a, b;
            unpack2(q.x, a, b); mx[8*t+0] = fmaxf(mx[8*t+0], a); mx[8*t+1] = fmaxf(mx[8*t+1], b);
            unpack2(q.y, a, b); mx[8*t+2] = fmaxf(mx[8*t+2], a); mx[8*t+3] = fmaxf(mx[8*t+3], b);
            unpack2(q.z, a, b); mx[8*t+4] = fmaxf(mx[8*t+4], a); mx[8*t+5] = fmaxf(mx[8*t+5], b);
            unpack2(q.w, a, b); mx[8*t+6] = fmaxf(mx[8*t+6], a); mx[8*t+7] = fmaxf(mx[8*t+7], b);
        }
    }
    float v1[32], vf[32], a1[32], o[20];
    dense<32, 32, true, true>(mx, v1, W + O_VE1W, W + O_VE1B);
    dense<32, 32, true, true>(v1, vf, W + O_VE2W, W + O_VE2B);
#pragma unroll
    for (int c = 0; c < 16; ++c) vf_u[(size_t)v * 16 + c] = pack2(vf[2*c], vf[2*c+1]);
    dense<32, 32, true, true>(v1, a1, W + O_AUX1W, W + O_AUX1B);
    dense<32, 20, false, false>(a1, o, W + O_AUX2W, nullptr);
    if (of32) {
        float* auxf = (float*)outbase + (size_t)NPTS * NCLS + (size_t)v * NCLS;
#pragma unroll
        for (int t = 0; t < NCLS; ++t) __builtin_nontemporal_store(o[t], auxf + t);
    } else {
        unsigned* auxu = (unsigned*)((bf16*)outbase + (size_t)NPTS * NCLS);
#pragma unroll
        for (int t = 0; t < 10; ++t) __builtin_nontemporal_store(pack2(o[2*t], o[2*t+1]), auxu + (size_t)v * 10 + t);
    }
}

// ---------- K3: fuse GEMM (direct-frag gather) + per-batch sums ----------
__global__ __launch_bounds__(256) void k3_mfma(const int* __restrict__ bid, const int* __restrict__ pv,
                                               const uint4* __restrict__ pf_q,
                                               const uint4* __restrict__ vf_q,
                                               const float* __restrict__ W,
                                               const unsigned short* __restrict__ WTfu,
                                               float* __restrict__ bsum8) {
    __shared__ int sbid[256];
    __shared__ float red[4][64];
    __shared__ int sflag;
    int t = threadIdx.x;
    int i0 = blockIdx.x * 256;
    int nval = NPTS - i0; if (nval > 256) nval = 256;   // multiple of 64
    if (t < nval) sbid[t] = bid[i0 + t];
    if (t == 0) sflag = (bid[i0] == bid[i0 + nval - 1]) ? 1 : 0;

    int lane = t & 63, w = t >> 6;
    int m = lane & 15, quad = lane >> 4;
    bf16x8_t bw0[4], bw1[4];
    float bias[4];
#pragma unroll
    for (int tn = 0; tn < 4; ++tn) {
        bw0[tn] = *(const bf16x8_t*)(WTfu + (tn * 16 + m) * 64 + quad * 8);
        bw1[tn] = *(const bf16x8_t*)(WTfu + (tn * 16 + m) * 64 + 32 + quad * 8);
        bias[tn] = W[O_FUB + tn * 16 + m];
    }
    __syncthreads();
    int uni = sflag;
    int b0 = sbid[0];
    int rep = (blockIdx.x & 7) * 256;
    int ntiles = (nval - w * 64 >= 64) ? 4 : 0;

    float csum[4] = {0.f, 0.f, 0.f, 0.f};
#pragma unroll
    for (int tt = 0; tt < 4; ++tt) {
        if (tt >= ntiles) break;
        int rbase = i0 + w * 64 + tt * 16;
        int arow = rbase + m;
        int pvr = pv[arow];
        uint4 va = vf_q[(size_t)pvr * 4 + quad];
        uint4 vb = pf_q[(size_t)arow * 4 + quad];
        bf16x8_t a0 = *(bf16x8_t*)&va;
        bf16x8_t a1 = *(bf16x8_t*)&vb;
        float f[4][4];
#pragma unroll
        for (int tn = 0; tn < 4; ++tn) {
            f32x4_t acc = {0.f, 0.f, 0.f, 0.f};
            acc = MFMA16(a0, bw0[tn], acc);
            acc = MFMA16(a1, bw1[tn], acc);
#pragma unroll
            for (int e = 0; e < 4; ++e) f[tn][e] = fmaxf(acc[e] + bias[tn], 0.f);
        }
        if (uni) {
#pragma unroll
            for (int tn = 0; tn < 4; ++tn) {
                float s = f[tn][0] + f[tn][1] + f[tn][2] + f[tn][3];
                s += __shfl_xor(s, 16);
                s += __shfl_xor(s, 32);
                csum[tn] += s;
            }
        } else {   // batch-boundary block (~3 total): per-row atomics
#pragma unroll
            for (int tn = 0; tn < 4; ++tn)
#pragma unroll
                for (int e = 0; e < 4; ++e)
                    atomicAdd(&bsum8[rep + sbid[rbase - i0 + quad * 4 + e] * 64 + tn * 16 + m], f[tn][e]);
        }
    }
    if (uni) {
        float mine = quad == 0 ? csum[0] : quad == 1 ? csum[1] : quad == 2 ? csum[2] : csum[3];
        red[w][quad * 16 + m] = mine;
        __syncthreads();
        if (t < 64) {
            float s = red[0][t] + red[1][t] + red[2][t] + red[3][t];
            atomicAdd(&bsum8[rep + b0 * 64 + t], s);
        }
    }
}

// ---------- K4: SE gate + batch-scaled cls1 weights (gate folded) ----------
__global__ void k4_gate(const float* __restrict__ bsum8, const float* __restrict__ bcnt,
                        const float* __restrict__ W, const unsigned short* __restrict__ WTc1,
                        float* __restrict__ gate, unsigned short* __restrict__ WTc1B) {
    __shared__ float m[4][64];
    __shared__ float hid[4][4];
    __shared__ float gl[256];
    int tid = threadIdx.x, b = tid >> 6, c = tid & 63;
    float s = 0.f;
#pragma unroll
    for (int r = 0; r < 8; ++r) s += bsum8[r * 256 + tid];
    m[b][c] = s / fmaxf(bcnt[b], 1.f);
    __syncthreads();
    if (c < 4) {
        const float* w = W + O_SE1W;
        float a = (W + O_SE1B)[c];
        for (int k = 0; k < 64; ++k) a = fmaf(m[b][k], w[k * 4 + c], a);
        hid[b][c] = fmaxf(a, 0.f);
    }
    __syncthreads();
    const float* w2 = W + O_SE2W;
    float g = (W + O_SE2B)[c];
#pragma unroll
    for (int h = 0; h < 4; ++h) g = fmaf(hid[b][h], w2[h * 64 + c], g);
    g = 1.f + 1.f / (1.f + expf(-g));   // (1 + sigmoid)
    gate[tid] = g;
    gl[tid] = g;
    __syncthreads();
    // WTc1B[b][n][k] = WTc1[n][k] * (1 + sigmoid(...))_b[k]   (exact gate fold:
    // relu(fused)*g @ W == relu(fused) @ diag(g) W)
    for (int idx = tid; idx < 8192; idx += 256) {
        int bb = idx >> 11, j = idx & 2047, k = j & 63;
        WTc1B[idx] = f2us(us2f(WTc1[j]) * gl[bb * 64 + k]);
    }
}

// ---------- K5: fuse GEMM + gate-folded cls GEMMs + store ----------
__global__ __launch_bounds__(256) void k5_mfma(const int* __restrict__ bid, const int* __restrict__ pv,
                                               const uint4* __restrict__ pf_q,
                                               const uint4* __restrict__ vf_q,
                                               const float* __restrict__ W,
                                               const unsigned short* __restrict__ WTfu,
                                               const unsigned short* __restrict__ WTc1,
                                               const unsigned short* __restrict__ WTc1B,
                                               const unsigned short* __restrict__ WTc2,
                                               const float* __restrict__ gate,
                                               const void* __restrict__ pts_raw,
                                               void* __restrict__ out) {
    __shared__ float sg[256];
    __shared__ int sbid[256];
    __shared__ int sflag;
    __shared__ __align__(16) unsigned short ft[4][16][72];
    __shared__ __align__(16) unsigned short ht[4][16][40];
    __shared__ float ot[4][16][20];
    int t = threadIdx.x;
    int i0 = blockIdx.x * 256;
    int nval = NPTS - i0; if (nval > 256) nval = 256;
    sg[t] = gate[t];
    if (t < nval) sbid[t] = bid[i0 + t];
    if (t == 0) sflag = (bid[i0] == bid[i0 + nval - 1]) ? 1 : 0;

    int lane = t & 63, w = t >> 6;
    int m = lane & 15, quad = lane >> 4;
    bf16x8_t bfu0[4], bfu1[4];
    float biasfu[4];
#pragma unroll
    for (int tn = 0; tn < 4; ++tn) {
        bfu0[tn] = *(const bf16x8_t*)(WTfu + (tn * 16 + m) * 64 + quad * 8);
        bfu1[tn] = *(const bf16x8_t*)(WTfu + (tn * 16 + m) * 64 + 32 + quad * 8);
        biasfu[tn] = W[O_FUB + tn * 16 + m];
    }
    __syncthreads();
    int uni = sflag;
    int b0 = sbid[0];
    int of32 = detect_fp32(pts_raw);
    int ntiles = (nval - w * 64 >= 64) ? 4 : 0;

    // cls1 frags: batch-scaled (gate-folded) for uniform blocks, raw otherwise
    const unsigned short* c1base = uni ? (WTc1B + b0 * 2048) : WTc1;
    bf16x8_t bc10[2], bc11[2], bc2[2];
    float biasc1[2];
#pragma unroll
    for (int tn = 0; tn < 2; ++tn) {
        bc10[tn] = *(const bf16x8_t*)(c1base + (tn * 16 + m) * 64 + quad * 8);
        bc11[tn] = *(const bf16x8_t*)(c1base + (tn * 16 + m) * 64 + 32 + quad * 8);
        bc2[tn]  = *(const bf16x8_t*)(WTc2 + (tn * 16 + m) * 32 + quad * 8);
        biasc1[tn] = W[O_CLS1B + tn * 16 + m];
    }

#pragma unroll 1
    for (int tt = 0; tt < ntiles; ++tt) {
        int rbase = i0 + w * 64 + tt * 16;
        int arow = rbase + m;
        int pvr = pv[arow];
        uint4 va = vf_q[(size_t)pvr * 4 + quad];
        uint4 vb = pf_q[(size_t)arow * 4 + quad];
        bf16x8_t a0 = *(bf16x8_t*)&va;
        bf16x8_t a1 = *(bf16x8_t*)&vb;
        // fuse 64->64 + relu (+ gate only in non-uniform blocks) -> ft
#pragma unroll
        for (int tn = 0; tn < 4; ++tn) {
            f32x4_t acc = {0.f, 0.f, 0.f, 0.f};
            acc = MFMA16(a0, bfu0[tn], acc);
            acc = MFMA16(a1, bfu1[tn], acc);
#pragma unroll
            for (int e = 0; e < 4; ++e) {
                float fv = fmaxf(acc[e] + biasfu[tn], 0.f);
                if (!uni) fv *= sg[sbid[rbase - i0 + quad * 4 + e] * 64 + tn * 16 + m];
                ft[w][quad * 4 + e][tn * 16 + m] = f2us(fv);
            }
        }
        // cls1 64->32 + relu -> ht  (gate folded into weights for uni blocks)
        bf16x8_t c0 = *(const bf16x8_t*)&ft[w][m][quad * 8];
        bf16x8_t c1 = *(const bf16x8_t*)&ft[w][m][32 + quad * 8];
#pragma unroll
        for (int tn = 0; tn < 2; ++tn) {
            f32x4_t acc = {0.f, 0.f, 0.f, 0.f};
            acc = MFMA16(c0, bc10[tn], acc);
            acc = MFMA16(c1, bc11[tn], acc);
#pragma unroll
            for (int e = 0; e < 4; ++e)
                ht[w][quad * 4 + e][tn * 16 + m] = f2us(fmaxf(acc[e] + biasc1[tn], 0.f));
        }
        // cls2 32->20
        bf16x8_t d0 = *(const bf16x8_t*)&ht[w][m][quad * 8];
#pragma unroll
        for (int tn = 0; tn < 2; ++tn) {
            f32x4_t acc = {0.f, 0.f, 0.f, 0.f};
            acc = MFMA16(d0, bc2[tn], acc);
            int c = tn * 16 + m;
            if (c < NCLS) {
#pragma unroll
                for (int e = 0; e < 4; ++e) ot[w][quad * 4 + e][c] = acc[e];
            }
        }
        // store 16 rows x 20 cols (wave-sync LDS readback, nontemporal)
        if (of32) {
            float* of = (float*)out + (size_t)rbase * NCLS;
#pragma unroll
            for (int k = 0; k < 5; ++k) {
                int idx = k * 64 + lane;
                __builtin_nontemporal_store(((const float*)ot[w])[idx], of + idx);
            }
        } else {
            unsigned* ow = (unsigned*)((unsigned short*)out + (size_t)rbase * NCLS);
#pragma unroll
            for (int k = 0; k < 3; ++k) {
                int idx = k * 64 + lane;
                if (idx < 160) {
                    int p = idx / 10, c2 = idx - p * 10;
                    __builtin_nontemporal_store(pack2(ot[w][p][2 * c2], ot[w][p][2 * c2 + 1]), ow + idx);
                }
            }
        }
    }
}

extern "C" void kernel_launch(void* const* d_in, const int* in_sizes, int n_in,
                              void* d_out, int out_size, void* d_ws, size_t ws_size,
                              hipStream_t stream) {
    WPtrs p;
    p.pe_w1 = d_in[2];  p.pe_g1 = d_in[3];  p.pe_b1 = d_in[4];
    p.pe_w2 = d_in[5];  p.pe_g2 = d_in[6];  p.pe_b2 = d_in[7];
    p.pe_w3 = d_in[8];  p.pe_g3 = d_in[9];  p.pe_b3 = d_in[10];
    p.ve_w1 = d_in[11]; p.ve_g1 = d_in[12]; p.ve_b1 = d_in[13];
    p.ve_w2 = d_in[14]; p.ve_g2 = d_in[15]; p.ve_b2 = d_in[16];
    p.fu_w  = d_in[17]; p.fu_g  = d_in[18]; p.fu_b  = d_in[19];
    p.se_w1 = d_in[20]; p.se_b1 = d_in[21];
    p.se_w2 = d_in[22]; p.se_b2 = d_in[23];
    p.cls_w1 = d_in[24]; p.cls_g1 = d_in[25]; p.cls_b1 = d_in[26];
    p.cls_w2 = d_in[27];
    p.aux_w1 = d_in[28]; p.aux_g1 = d_in[29]; p.aux_b1 = d_in[30];
    p.aux_w2 = d_in[31];

    float* base = (float*)d_ws;
    int*   pvN  = (int*)(base + L_PV);
    int*   bidN = (int*)(base + L_BID);
    int*   cnt  = (int*)(base + L_CNT);
    float* bsum8 = base + L_BSUM;
    float* bcnt = base + L_BCNT;
    float* gate = base + L_GATE;
    int*   offs = (int*)(base + L_OFFS);
    int*   bs1  = (int*)(base + L_BS1);
    int*   bb   = (int*)(base + L_BB);
    int*   rank = (int*)(base + L_IDX);
    float* W    = base + L_W;
    unsigned short* WT = (unsigned short*)(base + L_WT);
    unsigned short* wtfu = WT + WT_FU;
    unsigned short* wtc1 = WT + WT_C1;
    unsigned short* wtc2 = WT + WT_C2;
    unsigned short* wt2h = WT + WT_2H;
    unsigned short* wt2l = WT + WT_2L;
    unsigned short* wt3h = WT + WT_3H;
    unsigned short* wt3l = WT + WT_3L;
    unsigned short* wtc1b = WT + WT_C1B;
    unsigned* vf_u = (unsigned*)(base + L_VFU);
    uint4* pf_q = (uint4*)(base + L_PFQ);
    uint4* pf_s = (uint4*)(base + L_PFS);

    constexpr int NBV = (NVOX + 255) / 256;
    constexpr int NBS = (NVOX + 1023) / 1024;
    constexpr int NBM = (NPTS + 255) / 256;       // 3907 (last block 64 pts)
    constexpr int NBSC = (NPTS * 4 + 255) / 256;  // scatter: 4 lanes/point

    // zero cnt + bsum8 + bcnt (contiguous)
    hipMemsetAsync(cnt, 0, (NVOX + 2048 + 4) * sizeof(float), stream);
    k0_prep<<<1, 256, 0, stream>>>(p, d_in[0], W, WT);
    k1_fused<<<NBM, 256, 0, stream>>>(d_in[0], d_in[1], W, wt2h, wt2l, wt3h, wt3l,
                                      pvN, bidN, cnt, bcnt, rank, pf_q);
    k_scan1<<<NBS, 256, 0, stream>>>(cnt, bs1);
    k_scan2<<<1, 256, 0, stream>>>(bs1, bb, NBS);
    k_scan3<<<NBS, 256, 0, stream>>>(cnt, bb, offs);
    k_scat<<<NBSC, 256, 0, stream>>>(pvN, rank, offs, pf_q, pf_s);
    k_voxmlp<<<NBV, 256, 0, stream>>>(offs, cnt, pf_s, W, d_in[0], vf_u, d_out);
    k3_mfma<<<NBM, 256, 0, stream>>>(bidN, pvN, pf_q, (const uint4*)vf_u, W, wtfu, bsum8);
    k4_gate<<<1, 256, 0, stream>>>(bsum8, bcnt, W, wtc1, gate, wtc1b);
    k5_mfma<<<NBM, 256, 0, stream>>>(bidN, pvN, pf_q, (const uint4*)vf_u, W,
                                     wtfu, wtc1, wtc1b, wtc2, gate, d_in[0], d_out);
}